// Round 4
// baseline (7067.709 us; speedup 1.0000x reference)
//
#include <hip/hip_runtime.h>
#include <math.h>

// ---------------------------------------------------------------------------
// Pointer-network decoder, 50 sequential greedy-decode steps, bf16 MFMA.
// R4: (1) LSTM gates fused into a transposed, gate-interleaved MFMA GEMM
//     (C'[n'=4j+gate, b], K=1024 over [x|h] concat) -> no gates_kernel, no
//     16.8 MB fp32 g_ws round-trip. (2) pointer+combine fused (lp in LDS).
//     5 dispatches/step instead of 7.
// ---------------------------------------------------------------------------

#define S_LEN 50
#define BATCH 512
#define HDIM  512
#define BH    (BATCH*HDIM)          // 262144
#define BS    (BATCH*S_LEN)         // 25600
#define KSPQ  4                     // split-K for the small q GEMMs
#define XH_K  1024                  // [x|h] concat K
#define XH_Z  (BATCH*XH_K)          // per-z xh elements
#define NGATE 2048                  // gate rows
#define MASK50 0x0003FFFFFFFFFFFFULL

typedef unsigned short u16;
typedef __attribute__((ext_vector_type(8))) short bf16x8;
typedef __attribute__((ext_vector_type(4))) float f32x4;

__device__ __forceinline__ float wave_sum(float v){
  #pragma unroll
  for (int o=32;o;o>>=1) v += __shfl_xor(v,o);
  return v;
}
__device__ __forceinline__ float wave_max(float v){
  #pragma unroll
  for (int o=32;o;o>>=1) v = fmaxf(v,__shfl_xor(v,o));
  return v;
}
__device__ __forceinline__ float sigmoidf_(float x){ return 1.0f/(1.0f+expf(-x)); }
__device__ __forceinline__ u16 f2b(float f){
  unsigned u = __float_as_uint(f);
  unsigned r = (u + 0x7fffu + ((u>>16)&1u)) >> 16;
  return (u16)r;
}
__device__ __forceinline__ float b2f(u16 h){ return __uint_as_float(((unsigned)h)<<16); }

// ---------------------------------------------------------------------------
// Generic bf16 MFMA GEMM: C[m,n] = sum_k A[m,k]*W[n,k] (+bias[n]).
// A row stride = lda (>=K); W row stride = K. 128x128 tile, BK=64.
// ksplit: fp32 partial at C + ksp*M*N. out_bf16: bf16 store (ksplit==1).
// ---------------------------------------------------------------------------
struct MArgs {
  const u16* A[4]; const u16* W[4]; const float* bias[4]; void* C[4];
  int M, N, K, lda, ksplit, out_bf16;
};

__global__ __launch_bounds__(256, 2) void mfma_gemm(MArgs g) {
  const int z = blockIdx.z;
  const u16* __restrict__ A = g.A[z];
  const u16* __restrict__ W = g.W[z];
  const float* __restrict__ bias = g.bias[z];
  const int N = g.N, K = g.K, lda = g.lda;
  const int mtile = blockIdx.y / g.ksplit;
  const int ksp   = blockIdx.y % g.ksplit;
  const int m0 = mtile*128, n0 = blockIdx.x*128;
  const int kc = K / g.ksplit;
  const int kbeg = ksp*kc, kend = kbeg+kc;

  __shared__ __align__(16) u16 As[128*88];
  __shared__ __align__(16) u16 Bs[128*88];

  const int tid = threadIdx.x;
  const int wave = tid>>6, lane = tid&63;
  const int wm = (wave>>1)*64, wn = (wave&1)*64;
  const int m16 = lane&15, quad = lane>>4;

  f32x4 acc[4][4];
  #pragma unroll
  for (int i=0;i<4;i++)
    #pragma unroll
    for (int j=0;j<4;j++) acc[i][j] = (f32x4){0.f,0.f,0.f,0.f};

  for (int kt = kbeg; kt < kend; kt += 64) {
    uint4 av[4], wv[4];
    #pragma unroll
    for (int it=0; it<4; it++){
      int idx = tid + it*256;
      int r = idx>>3, c = idx&7;
      av[it] = *(const uint4*)(A + (size_t)(m0+r)*lda + kt + c*8);
      wv[it] = *(const uint4*)(W + (size_t)(n0+r)*K   + kt + c*8);
    }
    __syncthreads();
    #pragma unroll
    for (int it=0; it<4; it++){
      int idx = tid + it*256;
      int r = idx>>3, c = idx&7;
      *(uint4*)&As[r*88 + c*8] = av[it];
      *(uint4*)&Bs[r*88 + c*8] = wv[it];
    }
    __syncthreads();
    #pragma unroll
    for (int ks=0; ks<2; ks++){
      bf16x8 af[4], bf[4];
      #pragma unroll
      for (int i=0;i<4;i++) af[i] = *(const bf16x8*)&As[(wm + i*16 + m16)*88 + ks*32 + quad*8];
      #pragma unroll
      for (int j=0;j<4;j++) bf[j] = *(const bf16x8*)&Bs[(wn + j*16 + m16)*88 + ks*32 + quad*8];
      #pragma unroll
      for (int i=0;i<4;i++)
        #pragma unroll
        for (int j=0;j<4;j++)
          acc[i][j] = __builtin_amdgcn_mfma_f32_16x16x32_bf16(af[i], bf[j], acc[i][j], 0, 0, 0);
    }
  }

  if (g.out_bf16) {
    u16* C = (u16*)g.C[z];
    #pragma unroll
    for (int i=0;i<4;i++){
      int mb = m0 + wm + i*16 + quad*4;
      #pragma unroll
      for (int j=0;j<4;j++){
        int n = n0 + wn + j*16 + m16;
        float bv = bias ? bias[n] : 0.0f;
        #pragma unroll
        for (int r=0;r<4;r++)
          C[(size_t)(mb+r)*N + n] = f2b(acc[i][j][r] + bv);
      }
    }
  } else {
    float* C = (float*)g.C[z] + (size_t)ksp*g.M*N;
    #pragma unroll
    for (int i=0;i<4;i++){
      int mb = m0 + wm + i*16 + quad*4;
      #pragma unroll
      for (int j=0;j<4;j++){
        int n = n0 + wn + j*16 + m16;
        float bv = bias ? bias[n] : 0.0f;
        #pragma unroll
        for (int r=0;r<4;r++)
          C[(size_t)(mb+r)*N + n] = acc[i][j][r] + bv;
      }
    }
  }
}

// ---------------------------------------------------------------------------
// Fused LSTM step: G'[n'=4j+gate, b] = Wg[n',:]·xh[b,:] (K=1024), then gate
// nonlinearity in-register (lane's f32x4 = (i,f,g,o) for one (j,b)), updating
// c_ws fp32 and writing h bf16 into xh[...,512+j]. grid (4, 16, 2).
// Wg rows permuted: n' = 4j+g  <->  original gate row g*512+j, k = [Wih|Whh].
// ---------------------------------------------------------------------------
__global__ __launch_bounds__(256, 2) void lstm_step_kernel(
    const u16* __restrict__ Wg, const float* __restrict__ bsum,
    u16* __restrict__ xh, float* __restrict__ c_ws) {
  const int z = blockIdx.z;
  const u16* A = Wg + (size_t)z*NGATE*XH_K;
  const u16* B = xh + (size_t)z*XH_Z;
  const int n0 = blockIdx.x*128;   // batch
  const int m0 = blockIdx.y*128;   // gate rows

  __shared__ __align__(16) u16 As[128*88];
  __shared__ __align__(16) u16 Bs[128*88];

  const int tid = threadIdx.x;
  const int wave = tid>>6, lane = tid&63;
  const int wm = (wave>>1)*64, wn = (wave&1)*64;
  const int m16 = lane&15, quad = lane>>4;

  f32x4 acc[4][4];
  #pragma unroll
  for (int i=0;i<4;i++)
    #pragma unroll
    for (int j=0;j<4;j++) acc[i][j] = (f32x4){0.f,0.f,0.f,0.f};

  for (int kt = 0; kt < XH_K; kt += 64) {
    uint4 av[4], wv[4];
    #pragma unroll
    for (int it=0; it<4; it++){
      int idx = tid + it*256;
      int r = idx>>3, c = idx&7;
      av[it] = *(const uint4*)(A + (size_t)(m0+r)*XH_K + kt + c*8);
      wv[it] = *(const uint4*)(B + (size_t)(n0+r)*XH_K + kt + c*8);
    }
    __syncthreads();
    #pragma unroll
    for (int it=0; it<4; it++){
      int idx = tid + it*256;
      int r = idx>>3, c = idx&7;
      *(uint4*)&As[r*88 + c*8] = av[it];
      *(uint4*)&Bs[r*88 + c*8] = wv[it];
    }
    __syncthreads();
    #pragma unroll
    for (int ks=0; ks<2; ks++){
      bf16x8 af[4], bf[4];
      #pragma unroll
      for (int i=0;i<4;i++) af[i] = *(const bf16x8*)&As[(wm + i*16 + m16)*88 + ks*32 + quad*8];
      #pragma unroll
      for (int j=0;j<4;j++) bf[j] = *(const bf16x8*)&Bs[(wn + j*16 + m16)*88 + ks*32 + quad*8];
      #pragma unroll
      for (int i=0;i<4;i++)
        #pragma unroll
        for (int j=0;j<4;j++)
          acc[i][j] = __builtin_amdgcn_mfma_f32_16x16x32_bf16(af[i], bf[j], acc[i][j], 0, 0, 0);
    }
  }

  // epilogue: each acc[i][j] = (gi,gf,gg,go) for hidden j_idx, batch b
  #pragma unroll
  for (int i=0;i<4;i++){
    int mrow = m0 + wm + i*16 + quad*4;     // multiple of 4
    int j_idx = mrow >> 2;
    float b0 = bsum[z*NGATE + mrow+0];
    float b1 = bsum[z*NGATE + mrow+1];
    float b2 = bsum[z*NGATE + mrow+2];
    float b3 = bsum[z*NGATE + mrow+3];
    #pragma unroll
    for (int j=0;j<4;j++){
      int b = n0 + wn + j*16 + m16;
      float gi = acc[i][j][0] + b0;
      float gf = acc[i][j][1] + b1;
      float gg = acc[i][j][2] + b2;
      float go = acc[i][j][3] + b3;
      size_t cidx = (size_t)z*BH + (size_t)b*HDIM + j_idx;
      float c2 = sigmoidf_(gf)*c_ws[cidx] + sigmoidf_(gi)*tanhf(gg);
      c_ws[cidx] = c2;
      xh[(size_t)z*XH_Z + (size_t)b*XH_K + 512 + j_idx] = f2b(sigmoidf_(go)*tanhf(c2));
    }
  }
}

// ---------------------------------------------------------------------------
// fp32 -> bf16 copy (x4 vectorized)
// ---------------------------------------------------------------------------
__global__ void f2b_kernel(const float* __restrict__ src, u16* __restrict__ dst, int n4){
  int i = blockIdx.x*blockDim.x + threadIdx.x;
  if (i >= n4) return;
  float4 v = *(const float4*)(src + (size_t)i*4);
  ushort4 o; o.x=f2b(v.x); o.y=f2b(v.y); o.z=f2b(v.z); o.w=f2b(v.w);
  *(ushort4*)(dst + (size_t)i*4) = o;
}

// [S,B,H] fp32 -> [(b*S+s),H] bf16
__global__ void remap_kernel(const float* __restrict__ src, u16* __restrict__ dst){
  int i = blockIdx.x*blockDim.x + threadIdx.x;
  if (i >= (S_LEN*BATCH*HDIM)/4) return;
  int elem = i*4;
  int s = elem >> 18;
  int b = (elem >> 9) & 511;
  int h = elem & 511;
  float4 v = *(const float4*)(src + (size_t)s*BATCH*HDIM + (size_t)b*HDIM + h);
  ushort4 o; o.x=f2b(v.x); o.y=f2b(v.y); o.z=f2b(v.z); o.w=f2b(v.w);
  *(ushort4*)(dst + ((size_t)b*S_LEN + s)*HDIM + h) = o;
}

// Build permuted gate weights: Wg[n'=4j+g][k] = (k<512? Wih : Whh)[g*512+j][k%512]
// and bsum[n'] = bih[g*512+j] + bhh[g*512+j]. Launched once per z.
__global__ void build_wg_kernel(const float* __restrict__ Wih, const float* __restrict__ Whh,
                                const float* __restrict__ bih, const float* __restrict__ bhh,
                                u16* __restrict__ Wg, float* __restrict__ bsum){
  int i = blockIdx.x*blockDim.x + threadIdx.x;    // over 2048*256 uint4 groups
  if (i >= NGATE*(XH_K/4)) return;
  int np = i >> 8;            // n' row
  int kq = i & 255;
  int k = kq*4;
  int j = np >> 2, g = np & 3;
  int orig = g*512 + j;
  const float* src = (k < 512) ? (Wih + (size_t)orig*512 + k)
                               : (Whh + (size_t)orig*512 + (k-512));
  float4 v = *(const float4*)src;
  ushort4 o; o.x=f2b(v.x); o.y=f2b(v.y); o.z=f2b(v.z); o.w=f2b(v.w);
  *(ushort4*)(Wg + (size_t)np*XH_K + k) = o;
  if (kq == 0) bsum[np] = bih[orig] + bhh[orig];
}

// ---------------------------------------------------------------------------
// init: xh = [x|h0] bf16 (both z), c fp32, mask
// ---------------------------------------------------------------------------
__global__ void init_kernel(const float* __restrict__ h0, const float* __restrict__ c0,
                            const float* __restrict__ h0a, const float* __restrict__ c0a,
                            const float* __restrict__ dec, const unsigned char* __restrict__ vmask,
                            u16* __restrict__ xh, float* __restrict__ c_ws,
                            int* __restrict__ mask){
  for (int i = blockIdx.x*blockDim.x + threadIdx.x; i < BH; i += gridDim.x*blockDim.x) {
    int b = i >> 9, j = i & 511;
    u16 d = f2b(dec[i]);
    xh[(size_t)b*XH_K + j] = d;
    xh[(size_t)XH_Z + (size_t)b*XH_K + j] = d;
    xh[(size_t)b*XH_K + 512 + j] = f2b(h0[i]);
    xh[(size_t)XH_Z + (size_t)b*XH_K + 512 + j] = f2b(h0a[i]);
    c_ws[i] = c0[i]; c_ws[BH+i] = c0a[i];
    if (i < BS) mask[i] = vmask[i] ? 1 : 0;
  }
}

__global__ __launch_bounds__(64) void mask_fix_kernel(int* __restrict__ mask){
  int b = blockIdx.x, lane = threadIdx.x;
  int mv = (lane < S_LEN) ? mask[b*S_LEN+lane] : 1;
  unsigned long long bal = __ballot(mv != 0);
  if ((bal & MASK50) == MASK50 && lane == 49) mask[b*S_LEN+49] = 0;
}

// ---------------------------------------------------------------------------
// Glimpse attention on bf16 e [B,S,H]: logits+mask+softmax+weighted sum.
// ---------------------------------------------------------------------------
__global__ __launch_bounds__(512) void glimpse_kernel(
    const float* __restrict__ qpart,
    const float* __restrict__ bq_g, const float* __restrict__ bq_ga,
    const u16* __restrict__ e_g, const u16* __restrict__ e_ga,
    const float* __restrict__ v_g, const float* __restrict__ v_ga,
    const int* __restrict__ mask, u16* __restrict__ gl_ws){
  int z = blockIdx.y, b = blockIdx.x, tid = threadIdx.x;
  const u16* e = (z ? e_ga : e_g) + (size_t)b*S_LEN*HDIM;
  const float* v  = z ? v_ga : v_g;
  const float* bq = z ? bq_ga : bq_g;
  const float* qp = qpart + (size_t)z*KSPQ*BH + (size_t)b*HDIM;
  __shared__ float lg_sh[64], p_sh[64];
  int w = tid>>6, lane = tid&63;
  int h0 = lane*8;
  float qreg[8], vreg[8];
  #pragma unroll
  for (int ii=0; ii<8; ii++){
    int h = h0+ii;
    float q = bq[h];
    #pragma unroll
    for (int p=0;p<KSPQ;p++) q += qp[(size_t)p*BH + h];
    qreg[ii]=q; vreg[ii]=v[h];
  }
  for (int s = w; s < S_LEN; s += 8) {
    uint4 ev = *(const uint4*)(e + (size_t)s*HDIM + h0);
    const u16* pe = (const u16*)&ev;
    float acc = 0.0f;
    #pragma unroll
    for (int ii=0; ii<8; ii++) acc += vreg[ii]*tanhf(qreg[ii] + b2f(pe[ii]));
    acc = wave_sum(acc);
    if (lane==0) lg_sh[s] = mask[b*S_LEN+s] ? -INFINITY : acc;
  }
  __syncthreads();
  if (tid < 64) {
    float val = (tid < S_LEN) ? lg_sh[tid] : -INFINITY;
    float mx = wave_max(val);
    float ex = (tid < S_LEN) ? expf(val - mx) : 0.0f;
    float sm = wave_sum(ex);
    if (tid < S_LEN) p_sh[tid] = ex / sm;
  }
  __syncthreads();
  float acc = 0.0f;
  for (int s=0;s<S_LEN;s++) acc += p_sh[s]*b2f(e[(size_t)s*HDIM + tid]);
  gl_ws[(size_t)z*BH + (size_t)b*HDIM + tid] = f2b(acc);
}

// ---------------------------------------------------------------------------
// Fused pointer attention + combine. One block per b (512 thr):
// waves 0-3: z=0 lp, waves 4-7: z=1 lp (into LDS); wave 0: log_softmax both,
// combine, out write (clamped), argmax, mask update; all: gather next inputs.
// ---------------------------------------------------------------------------
__global__ __launch_bounds__(512) void pointer_combine_kernel(
    const float* __restrict__ qpart,
    const float* __restrict__ bq_p, const float* __restrict__ bq_pa,
    const u16* __restrict__ e_p, const u16* __restrict__ e_pa,
    const float* __restrict__ v_p, const float* __restrict__ v_pa,
    int* __restrict__ mask, float* __restrict__ out, int t,
    const u16* __restrict__ emb_bf, const u16* __restrict__ ench_bf,
    u16* __restrict__ xh){
  int b = blockIdx.x, tid = threadIdx.x;
  int wave = tid>>6, lane = tid&63;
  int z = wave>>2, wr = wave&3;
  __shared__ float lp_sh[128];
  __shared__ int idx_sh;
  if (tid < 128) lp_sh[tid] = -INFINITY;

  const u16* e = (z ? e_pa : e_p) + (size_t)b*S_LEN*HDIM;
  const float* v  = z ? v_pa : v_p;
  const float* bq = z ? bq_pa : bq_p;
  const float* qp = qpart + (size_t)z*KSPQ*BH + (size_t)b*HDIM;
  int h0 = lane*8;
  float qreg[8], vreg[8];
  #pragma unroll
  for (int ii=0; ii<8; ii++){
    int h = h0+ii;
    float q = bq[h];
    #pragma unroll
    for (int p=0;p<KSPQ;p++) q += qp[(size_t)p*BH + h];
    qreg[ii]=q; vreg[ii]=v[h];
  }
  __syncthreads();
  for (int s = wr; s < S_LEN; s += 4) {
    uint4 ev = *(const uint4*)(e + (size_t)s*HDIM + h0);
    const u16* pe = (const u16*)&ev;
    float acc = 0.0f;
    #pragma unroll
    for (int ii=0; ii<8; ii++) acc += vreg[ii]*tanhf(qreg[ii] + b2f(pe[ii]));
    acc = wave_sum(acc);
    if (lane==0) lp_sh[z*64 + s] = mask[b*S_LEN+s] ? -INFINITY : 10.0f*tanhf(acc);
  }
  __syncthreads();
  if (tid < 64) {
    float a  = lp_sh[lane];
    float ca = lp_sh[64+lane];
    float m1 = wave_max(a);
    float l1 = logf(wave_sum((a > -INFINITY) ? expf(a - m1) : 0.0f));
    float m2 = wave_max(ca);
    float l2 = logf(wave_sum((ca > -INFINITY) ? expf(ca - m2) : 0.0f));
    float logp = (a - m1 - l1) + 0.1f * (ca - m2 - l2);
    if (lane < S_LEN) out[(size_t)b*(S_LEN*S_LEN) + t*S_LEN + lane] = fmaxf(logp, -1e30f);
    float vv = (lane < S_LEN) ? logp : -INFINITY;
    int bi = lane;
    #pragma unroll
    for (int o=32;o;o>>=1) {
      float ov = __shfl_xor(vv, o); int oi = __shfl_xor(bi, o);
      if (ov > vv || (ov == vv && oi < bi)) { vv = ov; bi = oi; }
    }
    int idx = bi;
    if (lane == 0) { out[(size_t)BATCH*S_LEN*S_LEN + b*S_LEN + t] = (float)idx; idx_sh = idx; }
    // mask update for next step
    int mv = 1;
    if (lane < S_LEN) { mv = mask[b*S_LEN+lane]; if (lane==idx) mv = 1; mask[b*S_LEN+lane] = mv; }
    unsigned long long bal = __ballot(mv != 0);
    if ((bal & MASK50) == MASK50 && lane == 49) mask[b*S_LEN+49] = 0;
  }
  __syncthreads();
  int idx = idx_sh;
  xh[(size_t)b*XH_K + tid]        = emb_bf[((size_t)idx*BATCH + b)*HDIM + tid];
  xh[(size_t)XH_Z + (size_t)b*XH_K + tid] = ench_bf[((size_t)idx*BATCH + b)*HDIM + tid];
}

// ---------------------------------------------------------------------------
extern "C" void kernel_launch(void* const* d_in, const int* in_sizes, int n_in,
                              void* d_out, int out_size, void* d_ws, size_t ws_size,
                              hipStream_t stream) {
  (void)in_sizes; (void)n_in; (void)out_size; (void)ws_size;
  const float* dec    = (const float*)d_in[0];
  const float* emb    = (const float*)d_in[1];
  const float* h0     = (const float*)d_in[2];
  const float* c0     = (const float*)d_in[3];
  const float* ctx    = (const float*)d_in[4];
  const float* ench   = (const float*)d_in[5];
  const float* dia    = (const float*)d_in[6];
  const float* h0a    = (const float*)d_in[7];
  const float* c0a    = (const float*)d_in[8];
  const unsigned char* vmask = (const unsigned char*)d_in[9];
  const float* W_ih   = (const float*)d_in[10];
  const float* W_hh   = (const float*)d_in[11];
  const float* b_ih   = (const float*)d_in[12];
  const float* b_hh   = (const float*)d_in[13];
  const float* W_ih_a = (const float*)d_in[14];
  const float* W_hh_a = (const float*)d_in[15];
  const float* b_ih_a = (const float*)d_in[16];
  const float* b_hh_a = (const float*)d_in[17];
  const float* Wq_p  = (const float*)d_in[18];
  const float* bq_p  = (const float*)d_in[19];
  const float* Wr_p  = (const float*)d_in[20];
  const float* br_p  = (const float*)d_in[21];
  const float* v_p   = (const float*)d_in[22];
  const float* Wq_pa = (const float*)d_in[23];
  const float* bq_pa = (const float*)d_in[24];
  const float* Wr_pa = (const float*)d_in[25];
  const float* br_pa = (const float*)d_in[26];
  const float* v_pa  = (const float*)d_in[27];
  const float* Wq_g  = (const float*)d_in[28];
  const float* bq_g  = (const float*)d_in[29];
  const float* Wr_g  = (const float*)d_in[30];
  const float* br_g  = (const float*)d_in[31];
  const float* v_g   = (const float*)d_in[32];
  const float* Wq_ga = (const float*)d_in[33];
  const float* bq_ga = (const float*)d_in[34];
  const float* Wr_ga = (const float*)d_in[35];
  const float* br_ga = (const float*)d_in[36];
  const float* v_ga  = (const float*)d_in[37];

  char* base = (char*)d_ws;
  size_t off = 0;
  auto carve = [&](size_t bytes)->char*{ char* p = base + off; off += (bytes + 255) & ~(size_t)255; return p; };

  const size_t E_BYTES = (size_t)BS*HDIM*2;
  u16* e_g   = (u16*)carve(E_BYTES);
  u16* e_p   = (u16*)carve(E_BYTES);
  u16* e_ga  = (u16*)carve(E_BYTES);
  u16* e_pa  = (u16*)carve(E_BYTES);
  char* scratch = carve(2*E_BYTES);              // A_ctx/A_dia, later emb/ench bf16
  u16* A_ctx  = (u16*)scratch;
  u16* A_dia  = (u16*)(scratch + E_BYTES);
  u16* emb_bf  = A_ctx;
  u16* ench_bf = A_dia;
  u16* Wg      = (u16*)carve((size_t)2*NGATE*XH_K*2);   // permuted gate weights
  float* bsum  = (float*)carve((size_t)2*NGATE*4);
  u16* Wqg_bf  = (u16*)carve((size_t)BH*2);
  u16* Wqga_bf = (u16*)carve((size_t)BH*2);
  u16* Wqp_bf  = (u16*)carve((size_t)BH*2);
  u16* Wqpa_bf = (u16*)carve((size_t)BH*2);
  u16* Wrg_bf  = (u16*)carve((size_t)BH*2);
  u16* Wrp_bf  = (u16*)carve((size_t)BH*2);
  u16* Wrga_bf = (u16*)carve((size_t)BH*2);
  u16* Wrpa_bf = (u16*)carve((size_t)BH*2);
  u16* xh      = (u16*)carve((size_t)2*XH_Z*2);   // [2][B][1024] = [x|h]
  float* c_ws  = (float*)carve((size_t)2*BH*4);
  u16* gl      = (u16*)carve((size_t)2*BH*2);
  float* q_ws  = (float*)carve((size_t)2*KSPQ*BH*4);
  float* q2_ws = (float*)carve((size_t)2*KSPQ*BH*4);
  int*   mask  = (int*)carve((size_t)BS*4);
  float* out   = (float*)d_out;

  init_kernel<<<1024, 256, 0, stream>>>(h0, c0, h0a, c0a, dec, vmask, xh, c_ws, mask);
  mask_fix_kernel<<<BATCH, 64, 0, stream>>>(mask);

  // prologue conversions
  const int RB = ((S_LEN*BATCH*HDIM/4)+255)/256;
  remap_kernel<<<RB, 256, 0, stream>>>(ctx, A_ctx);
  remap_kernel<<<RB, 256, 0, stream>>>(dia, A_dia);
  const int NWG = NGATE*(XH_K/4);
  build_wg_kernel<<<(NWG+255)/256, 256, 0, stream>>>(W_ih,   W_hh,   b_ih,   b_hh,   Wg,                        bsum);
  build_wg_kernel<<<(NWG+255)/256, 256, 0, stream>>>(W_ih_a, W_hh_a, b_ih_a, b_hh_a, Wg + (size_t)NGATE*XH_K,   bsum + NGATE);
  const int NWQ = BH/4;
  f2b_kernel<<<(NWQ+255)/256, 256, 0, stream>>>(Wq_g,  Wqg_bf,  NWQ);
  f2b_kernel<<<(NWQ+255)/256, 256, 0, stream>>>(Wq_ga, Wqga_bf, NWQ);
  f2b_kernel<<<(NWQ+255)/256, 256, 0, stream>>>(Wq_p,  Wqp_bf,  NWQ);
  f2b_kernel<<<(NWQ+255)/256, 256, 0, stream>>>(Wq_pa, Wqpa_bf, NWQ);
  f2b_kernel<<<(NWQ+255)/256, 256, 0, stream>>>(Wr_g,  Wrg_bf,  NWQ);
  f2b_kernel<<<(NWQ+255)/256, 256, 0, stream>>>(Wr_p,  Wrp_bf,  NWQ);
  f2b_kernel<<<(NWQ+255)/256, 256, 0, stream>>>(Wr_ga, Wrga_bf, NWQ);
  f2b_kernel<<<(NWQ+255)/256, 256, 0, stream>>>(Wr_pa, Wrpa_bf, NWQ);

  // hoisted context projections -> e bf16 [b*S+s, H]
  MArgs pa{};
  pa.A[0]=A_ctx; pa.A[1]=A_ctx; pa.A[2]=A_dia; pa.A[3]=A_dia;
  pa.W[0]=Wrg_bf; pa.W[1]=Wrp_bf; pa.W[2]=Wrga_bf; pa.W[3]=Wrpa_bf;
  pa.bias[0]=br_g; pa.bias[1]=br_p; pa.bias[2]=br_ga; pa.bias[3]=br_pa;
  pa.C[0]=e_g; pa.C[1]=e_p; pa.C[2]=e_ga; pa.C[3]=e_pa;
  pa.M=BS; pa.N=HDIM; pa.K=HDIM; pa.lda=HDIM; pa.ksplit=1; pa.out_bf16=1;
  mfma_gemm<<<dim3(4,200,4), 256, 0, stream>>>(pa);

  // emb/ench bf16 into the now-dead A_ctx/A_dia space
  const int NE = S_LEN*BATCH*HDIM/4;
  f2b_kernel<<<(NE+255)/256, 256, 0, stream>>>(emb,  emb_bf,  NE);
  f2b_kernel<<<(NE+255)/256, 256, 0, stream>>>(ench, ench_bf, NE);

  // per-step q GEMM args
  MArgs qg{};
  qg.A[0]=xh+512; qg.A[1]=xh+XH_Z+512;           // h part of [x|h], lda=1024
  qg.W[0]=Wqg_bf; qg.W[1]=Wqga_bf;
  qg.bias[0]=qg.bias[1]=qg.bias[2]=qg.bias[3]=nullptr;
  qg.C[0]=q_ws; qg.C[1]=q_ws+(size_t)KSPQ*BH;
  qg.M=BATCH; qg.N=HDIM; qg.K=HDIM; qg.lda=XH_K; qg.ksplit=KSPQ; qg.out_bf16=0;

  MArgs qp{};
  qp.A[0]=gl; qp.A[1]=gl+BH;
  qp.W[0]=Wqp_bf; qp.W[1]=Wqpa_bf;
  qp.bias[0]=qp.bias[1]=qp.bias[2]=qp.bias[3]=nullptr;
  qp.C[0]=q2_ws; qp.C[1]=q2_ws+(size_t)KSPQ*BH;
  qp.M=BATCH; qp.N=HDIM; qp.K=HDIM; qp.lda=HDIM; qp.ksplit=KSPQ; qp.out_bf16=0;

  for (int t = 0; t < S_LEN; ++t) {
    lstm_step_kernel<<<dim3(4,16,2), 256, 0, stream>>>(Wg, bsum, xh, c_ws);
    mfma_gemm<<<dim3(4,4*KSPQ,2), 256, 0, stream>>>(qg);
    glimpse_kernel<<<dim3(BATCH,2), 512, 0, stream>>>(q_ws, bq_g, bq_ga, e_g, e_ga, v_g, v_ga, mask, gl);
    mfma_gemm<<<dim3(4,4*KSPQ,2), 256, 0, stream>>>(qp);
    pointer_combine_kernel<<<BATCH, 512, 0, stream>>>(q2_ws, bq_p, bq_pa, e_p, e_pa, v_p, v_pa,
                                                      mask, out, t, emb_bf, ench_bf, xh);
  }
}

// Round 5
// 6443.492 us; speedup vs baseline: 1.0969x; 1.0969x over previous
//
#include <hip/hip_runtime.h>
#include <math.h>

// ---------------------------------------------------------------------------
// Pointer-network decoder, 50 sequential greedy-decode steps, bf16 MFMA.
// R5: fused LSTM GEMM regeometried: 128(gates)x64(batch) tiles -> 256 blocks
//     (full GPU; R4's 128x128 gave only 128 blocks = half idle). Epilogue
//     coalesced: c-state in transposed [z][j][b] layout (64B contiguous per
//     quad), h staged through LDS -> uint4 row-segment stores into xh.
//     5 dispatches/step: lstm, qg-gemm, glimpse, qp-gemm, pointer+combine.
// ---------------------------------------------------------------------------

#define S_LEN 50
#define BATCH 512
#define HDIM  512
#define BH    (BATCH*HDIM)          // 262144
#define BS    (BATCH*S_LEN)         // 25600
#define KSPQ  4                     // split-K for the small q GEMMs
#define XH_K  1024                  // [x|h] concat K
#define XH_Z  (BATCH*XH_K)          // per-z xh elements
#define NGATE 2048                  // gate rows
#define MASK50 0x0003FFFFFFFFFFFFULL

typedef unsigned short u16;
typedef __attribute__((ext_vector_type(8))) short bf16x8;
typedef __attribute__((ext_vector_type(4))) float f32x4;

__device__ __forceinline__ float wave_sum(float v){
  #pragma unroll
  for (int o=32;o;o>>=1) v += __shfl_xor(v,o);
  return v;
}
__device__ __forceinline__ float wave_max(float v){
  #pragma unroll
  for (int o=32;o;o>>=1) v = fmaxf(v,__shfl_xor(v,o));
  return v;
}
__device__ __forceinline__ float sigmoidf_(float x){ return 1.0f/(1.0f+expf(-x)); }
__device__ __forceinline__ u16 f2b(float f){
  unsigned u = __float_as_uint(f);
  unsigned r = (u + 0x7fffu + ((u>>16)&1u)) >> 16;
  return (u16)r;
}
__device__ __forceinline__ float b2f(u16 h){ return __uint_as_float(((unsigned)h)<<16); }

// ---------------------------------------------------------------------------
// Generic bf16 MFMA GEMM: C[m,n] = sum_k A[m,k]*W[n,k] (+bias[n]).
// A row stride = lda; W row stride = K. 128x128 tile, BK=64.
// ksplit: fp32 partial at C + ksp*M*N. out_bf16: bf16 store (ksplit==1).
// ---------------------------------------------------------------------------
struct MArgs {
  const u16* A[4]; const u16* W[4]; const float* bias[4]; void* C[4];
  int M, N, K, lda, ksplit, out_bf16;
};

__global__ __launch_bounds__(256, 2) void mfma_gemm(MArgs g) {
  const int z = blockIdx.z;
  const u16* __restrict__ A = g.A[z];
  const u16* __restrict__ W = g.W[z];
  const float* __restrict__ bias = g.bias[z];
  const int N = g.N, K = g.K, lda = g.lda;
  const int mtile = blockIdx.y / g.ksplit;
  const int ksp   = blockIdx.y % g.ksplit;
  const int m0 = mtile*128, n0 = blockIdx.x*128;
  const int kc = K / g.ksplit;
  const int kbeg = ksp*kc, kend = kbeg+kc;

  __shared__ __align__(16) u16 As[128*88];
  __shared__ __align__(16) u16 Bs[128*88];

  const int tid = threadIdx.x;
  const int wave = tid>>6, lane = tid&63;
  const int wm = (wave>>1)*64, wn = (wave&1)*64;
  const int m16 = lane&15, quad = lane>>4;

  f32x4 acc[4][4];
  #pragma unroll
  for (int i=0;i<4;i++)
    #pragma unroll
    for (int j=0;j<4;j++) acc[i][j] = (f32x4){0.f,0.f,0.f,0.f};

  for (int kt = kbeg; kt < kend; kt += 64) {
    uint4 av[4], wv[4];
    #pragma unroll
    for (int it=0; it<4; it++){
      int idx = tid + it*256;
      int r = idx>>3, c = idx&7;
      av[it] = *(const uint4*)(A + (size_t)(m0+r)*lda + kt + c*8);
      wv[it] = *(const uint4*)(W + (size_t)(n0+r)*K   + kt + c*8);
    }
    __syncthreads();
    #pragma unroll
    for (int it=0; it<4; it++){
      int idx = tid + it*256;
      int r = idx>>3, c = idx&7;
      *(uint4*)&As[r*88 + c*8] = av[it];
      *(uint4*)&Bs[r*88 + c*8] = wv[it];
    }
    __syncthreads();
    #pragma unroll
    for (int ks=0; ks<2; ks++){
      bf16x8 af[4], bf[4];
      #pragma unroll
      for (int i=0;i<4;i++) af[i] = *(const bf16x8*)&As[(wm + i*16 + m16)*88 + ks*32 + quad*8];
      #pragma unroll
      for (int j=0;j<4;j++) bf[j] = *(const bf16x8*)&Bs[(wn + j*16 + m16)*88 + ks*32 + quad*8];
      #pragma unroll
      for (int i=0;i<4;i++)
        #pragma unroll
        for (int j=0;j<4;j++)
          acc[i][j] = __builtin_amdgcn_mfma_f32_16x16x32_bf16(af[i], bf[j], acc[i][j], 0, 0, 0);
    }
  }

  if (g.out_bf16) {
    u16* C = (u16*)g.C[z];
    #pragma unroll
    for (int i=0;i<4;i++){
      int mb = m0 + wm + i*16 + quad*4;
      #pragma unroll
      for (int j=0;j<4;j++){
        int n = n0 + wn + j*16 + m16;
        float bv = bias ? bias[n] : 0.0f;
        #pragma unroll
        for (int r=0;r<4;r++)
          C[(size_t)(mb+r)*N + n] = f2b(acc[i][j][r] + bv);
      }
    }
  } else {
    float* C = (float*)g.C[z] + (size_t)ksp*g.M*N;
    #pragma unroll
    for (int i=0;i<4;i++){
      int mb = m0 + wm + i*16 + quad*4;
      #pragma unroll
      for (int j=0;j<4;j++){
        int n = n0 + wn + j*16 + m16;
        float bv = bias ? bias[n] : 0.0f;
        #pragma unroll
        for (int r=0;r<4;r++)
          C[(size_t)(mb+r)*N + n] = acc[i][j][r] + bv;
      }
    }
  }
}

// ---------------------------------------------------------------------------
// Fused LSTM step, 128(gate rows) x 64(batch) tile, K=1024 over [x|h].
// grid (8 batch-tiles, 16 gate-tiles, 2 cells) = 256 blocks.
// Wg rows permuted n'=4j+g <-> orig g*512+j; lane's f32x4 = (i,f,g,o) of one
// (j, b). c stored transposed [z][j][b] (coalesced). h transposed via LDS,
// stored as uint4 row segments into xh[b][512+j].
// ---------------------------------------------------------------------------
__global__ __launch_bounds__(256, 2) void lstm_step_kernel(
    const u16* __restrict__ Wg, const float* __restrict__ bsum,
    u16* __restrict__ xh, float* __restrict__ c_t) {
  const int z = blockIdx.z;
  const u16* A = Wg + (size_t)z*NGATE*XH_K;
  const u16* B = xh + (size_t)z*XH_Z;
  const int n0 = blockIdx.x*64;    // batch
  const int m0 = blockIdx.y*128;   // gate rows

  __shared__ __align__(16) u16 As[128*88];
  __shared__ __align__(16) u16 Bs[64*88];
  __shared__ __align__(16) u16 h_sh[64*40];   // [b_loc][j_loc], stride 40

  const int tid = threadIdx.x;
  const int wave = tid>>6, lane = tid&63;
  const int wm = (wave>>1)*64, wn = (wave&1)*32;
  const int m16 = lane&15, quad = lane>>4;

  f32x4 acc[4][2];
  #pragma unroll
  for (int i=0;i<4;i++)
    #pragma unroll
    for (int j=0;j<2;j++) acc[i][j] = (f32x4){0.f,0.f,0.f,0.f};

  for (int kt = 0; kt < XH_K; kt += 64) {
    uint4 av[4], wv[2];
    #pragma unroll
    for (int it=0; it<4; it++){
      int idx = tid + it*256;
      int r = idx>>3, c = idx&7;
      av[it] = *(const uint4*)(A + (size_t)(m0+r)*XH_K + kt + c*8);
    }
    #pragma unroll
    for (int it=0; it<2; it++){
      int idx = tid + it*256;
      int r = idx>>3, c = idx&7;
      wv[it] = *(const uint4*)(B + (size_t)(n0+r)*XH_K + kt + c*8);
    }
    __syncthreads();
    #pragma unroll
    for (int it=0; it<4; it++){
      int idx = tid + it*256;
      int r = idx>>3, c = idx&7;
      *(uint4*)&As[r*88 + c*8] = av[it];
    }
    #pragma unroll
    for (int it=0; it<2; it++){
      int idx = tid + it*256;
      int r = idx>>3, c = idx&7;
      *(uint4*)&Bs[r*88 + c*8] = wv[it];
    }
    __syncthreads();
    #pragma unroll
    for (int ks=0; ks<2; ks++){
      bf16x8 af[4], bf[2];
      #pragma unroll
      for (int i=0;i<4;i++) af[i] = *(const bf16x8*)&As[(wm + i*16 + m16)*88 + ks*32 + quad*8];
      #pragma unroll
      for (int j=0;j<2;j++) bf[j] = *(const bf16x8*)&Bs[(wn + j*16 + m16)*88 + ks*32 + quad*8];
      #pragma unroll
      for (int i=0;i<4;i++)
        #pragma unroll
        for (int j=0;j<2;j++)
          acc[i][j] = __builtin_amdgcn_mfma_f32_16x16x32_bf16(af[i], bf[j], acc[i][j], 0, 0, 0);
    }
  }

  // epilogue: acc[i][jt] = (gi,gf,gg,go) for j_idx, batch b
  #pragma unroll
  for (int i=0;i<4;i++){
    int mrow = m0 + wm + i*16 + quad*4;     // multiple of 4
    int j_idx = mrow >> 2;
    float b0 = bsum[z*NGATE + mrow+0];
    float b1 = bsum[z*NGATE + mrow+1];
    float b2 = bsum[z*NGATE + mrow+2];
    float b3 = bsum[z*NGATE + mrow+3];
    int j_loc = (wm>>2) + i*4 + quad;       // 0..31
    #pragma unroll
    for (int jt=0;jt<2;jt++){
      int b_loc = wn + jt*16 + m16;         // 0..63
      int b = n0 + b_loc;
      float gi = acc[i][jt][0] + b0;
      float gf = acc[i][jt][1] + b1;
      float gg = acc[i][jt][2] + b2;
      float go = acc[i][jt][3] + b3;
      size_t cidx = (size_t)z*BH + (size_t)j_idx*BATCH + b;   // quad: 16 contig
      float c2 = sigmoidf_(gf)*c_t[cidx] + sigmoidf_(gi)*tanhf(gg);
      c_t[cidx] = c2;
      h_sh[b_loc*40 + j_loc] = f2b(sigmoidf_(go)*tanhf(c2));
    }
  }
  __syncthreads();
  {
    int b_loc = tid>>2, jseg = (tid&3)*8;
    uint4 hv = *(const uint4*)&h_sh[b_loc*40 + jseg];
    *(uint4*)&xh[(size_t)z*XH_Z + (size_t)(n0+b_loc)*XH_K + 512 + (m0>>2) + jseg] = hv;
  }
}

// ---------------------------------------------------------------------------
__global__ void f2b_kernel(const float* __restrict__ src, u16* __restrict__ dst, int n4){
  int i = blockIdx.x*blockDim.x + threadIdx.x;
  if (i >= n4) return;
  float4 v = *(const float4*)(src + (size_t)i*4);
  ushort4 o; o.x=f2b(v.x); o.y=f2b(v.y); o.z=f2b(v.z); o.w=f2b(v.w);
  *(ushort4*)(dst + (size_t)i*4) = o;
}

// [S,B,H] fp32 -> [(b*S+s),H] bf16
__global__ void remap_kernel(const float* __restrict__ src, u16* __restrict__ dst){
  int i = blockIdx.x*blockDim.x + threadIdx.x;
  if (i >= (S_LEN*BATCH*HDIM)/4) return;
  int elem = i*4;
  int s = elem >> 18;
  int b = (elem >> 9) & 511;
  int h = elem & 511;
  float4 v = *(const float4*)(src + (size_t)s*BATCH*HDIM + (size_t)b*HDIM + h);
  ushort4 o; o.x=f2b(v.x); o.y=f2b(v.y); o.z=f2b(v.z); o.w=f2b(v.w);
  *(ushort4*)(dst + ((size_t)b*S_LEN + s)*HDIM + h) = o;
}

// Wg[n'=4j+g][k] = (k<512? Wih : Whh)[g*512+j][k%512]; bsum[n'] = bih+bhh.
__global__ void build_wg_kernel(const float* __restrict__ Wih, const float* __restrict__ Whh,
                                const float* __restrict__ bih, const float* __restrict__ bhh,
                                u16* __restrict__ Wg, float* __restrict__ bsum){
  int i = blockIdx.x*blockDim.x + threadIdx.x;
  if (i >= NGATE*(XH_K/4)) return;
  int np = i >> 8;
  int kq = i & 255;
  int k = kq*4;
  int j = np >> 2, g = np & 3;
  int orig = g*512 + j;
  const float* src = (k < 512) ? (Wih + (size_t)orig*512 + k)
                               : (Whh + (size_t)orig*512 + (k-512));
  float4 v = *(const float4*)src;
  ushort4 o; o.x=f2b(v.x); o.y=f2b(v.y); o.z=f2b(v.z); o.w=f2b(v.w);
  *(ushort4*)(Wg + (size_t)np*XH_K + k) = o;
  if (kq == 0) bsum[np] = bih[orig] + bhh[orig];
}

// init: xh = [x|h0] bf16, c transposed [z][j][b] fp32, mask
__global__ void init_kernel(const float* __restrict__ h0, const float* __restrict__ c0,
                            const float* __restrict__ h0a, const float* __restrict__ c0a,
                            const float* __restrict__ dec, const unsigned char* __restrict__ vmask,
                            u16* __restrict__ xh, float* __restrict__ c_t,
                            int* __restrict__ mask){
  for (int i = blockIdx.x*blockDim.x + threadIdx.x; i < BH; i += gridDim.x*blockDim.x) {
    int b = i >> 9, j = i & 511;
    u16 d = f2b(dec[i]);
    xh[(size_t)b*XH_K + j] = d;
    xh[(size_t)XH_Z + (size_t)b*XH_K + j] = d;
    xh[(size_t)b*XH_K + 512 + j] = f2b(h0[i]);
    xh[(size_t)XH_Z + (size_t)b*XH_K + 512 + j] = f2b(h0a[i]);
    c_t[(size_t)j*BATCH + b] = c0[i];
    c_t[BH + (size_t)j*BATCH + b] = c0a[i];
    if (i < BS) mask[i] = vmask[i] ? 1 : 0;
  }
}

__global__ __launch_bounds__(64) void mask_fix_kernel(int* __restrict__ mask){
  int b = blockIdx.x, lane = threadIdx.x;
  int mv = (lane < S_LEN) ? mask[b*S_LEN+lane] : 1;
  unsigned long long bal = __ballot(mv != 0);
  if ((bal & MASK50) == MASK50 && lane == 49) mask[b*S_LEN+49] = 0;
}

// ---------------------------------------------------------------------------
// Glimpse attention on bf16 e [B,S,H]
// ---------------------------------------------------------------------------
__global__ __launch_bounds__(512) void glimpse_kernel(
    const float* __restrict__ qpart,
    const float* __restrict__ bq_g, const float* __restrict__ bq_ga,
    const u16* __restrict__ e_g, const u16* __restrict__ e_ga,
    const float* __restrict__ v_g, const float* __restrict__ v_ga,
    const int* __restrict__ mask, u16* __restrict__ gl_ws){
  int z = blockIdx.y, b = blockIdx.x, tid = threadIdx.x;
  const u16* e = (z ? e_ga : e_g) + (size_t)b*S_LEN*HDIM;
  const float* v  = z ? v_ga : v_g;
  const float* bq = z ? bq_ga : bq_g;
  const float* qp = qpart + (size_t)z*KSPQ*BH + (size_t)b*HDIM;
  __shared__ float lg_sh[64], p_sh[64];
  int w = tid>>6, lane = tid&63;
  int h0 = lane*8;
  float qreg[8], vreg[8];
  #pragma unroll
  for (int ii=0; ii<8; ii++){
    int h = h0+ii;
    float q = bq[h];
    #pragma unroll
    for (int p=0;p<KSPQ;p++) q += qp[(size_t)p*BH + h];
    qreg[ii]=q; vreg[ii]=v[h];
  }
  for (int s = w; s < S_LEN; s += 8) {
    uint4 ev = *(const uint4*)(e + (size_t)s*HDIM + h0);
    const u16* pe = (const u16*)&ev;
    float acc = 0.0f;
    #pragma unroll
    for (int ii=0; ii<8; ii++) acc += vreg[ii]*tanhf(qreg[ii] + b2f(pe[ii]));
    acc = wave_sum(acc);
    if (lane==0) lg_sh[s] = mask[b*S_LEN+s] ? -INFINITY : acc;
  }
  __syncthreads();
  if (tid < 64) {
    float val = (tid < S_LEN) ? lg_sh[tid] : -INFINITY;
    float mx = wave_max(val);
    float ex = (tid < S_LEN) ? expf(val - mx) : 0.0f;
    float sm = wave_sum(ex);
    if (tid < S_LEN) p_sh[tid] = ex / sm;
  }
  __syncthreads();
  float acc = 0.0f;
  for (int s=0;s<S_LEN;s++) acc += p_sh[s]*b2f(e[(size_t)s*HDIM + tid]);
  gl_ws[(size_t)z*BH + (size_t)b*HDIM + tid] = f2b(acc);
}

// ---------------------------------------------------------------------------
// Fused pointer attention + combine
// ---------------------------------------------------------------------------
__global__ __launch_bounds__(512) void pointer_combine_kernel(
    const float* __restrict__ qpart,
    const float* __restrict__ bq_p, const float* __restrict__ bq_pa,
    const u16* __restrict__ e_p, const u16* __restrict__ e_pa,
    const float* __restrict__ v_p, const float* __restrict__ v_pa,
    int* __restrict__ mask, float* __restrict__ out, int t,
    const u16* __restrict__ emb_bf, const u16* __restrict__ ench_bf,
    u16* __restrict__ xh){
  int b = blockIdx.x, tid = threadIdx.x;
  int wave = tid>>6, lane = tid&63;
  int z = wave>>2, wr = wave&3;
  __shared__ float lp_sh[128];
  __shared__ int idx_sh;
  if (tid < 128) lp_sh[tid] = -INFINITY;

  const u16* e = (z ? e_pa : e_p) + (size_t)b*S_LEN*HDIM;
  const float* v  = z ? v_pa : v_p;
  const float* bq = z ? bq_pa : bq_p;
  const float* qp = qpart + (size_t)z*KSPQ*BH + (size_t)b*HDIM;
  int h0 = lane*8;
  float qreg[8], vreg[8];
  #pragma unroll
  for (int ii=0; ii<8; ii++){
    int h = h0+ii;
    float q = bq[h];
    #pragma unroll
    for (int p=0;p<KSPQ;p++) q += qp[(size_t)p*BH + h];
    qreg[ii]=q; vreg[ii]=v[h];
  }
  __syncthreads();
  for (int s = wr; s < S_LEN; s += 4) {
    uint4 ev = *(const uint4*)(e + (size_t)s*HDIM + h0);
    const u16* pe = (const u16*)&ev;
    float acc = 0.0f;
    #pragma unroll
    for (int ii=0; ii<8; ii++) acc += vreg[ii]*tanhf(qreg[ii] + b2f(pe[ii]));
    acc = wave_sum(acc);
    if (lane==0) lp_sh[z*64 + s] = mask[b*S_LEN+s] ? -INFINITY : 10.0f*tanhf(acc);
  }
  __syncthreads();
  if (tid < 64) {
    float a  = lp_sh[lane];
    float ca = lp_sh[64+lane];
    float m1 = wave_max(a);
    float l1 = logf(wave_sum((a > -INFINITY) ? expf(a - m1) : 0.0f));
    float m2 = wave_max(ca);
    float l2 = logf(wave_sum((ca > -INFINITY) ? expf(ca - m2) : 0.0f));
    float logp = (a - m1 - l1) + 0.1f * (ca - m2 - l2);
    if (lane < S_LEN) out[(size_t)b*(S_LEN*S_LEN) + t*S_LEN + lane] = fmaxf(logp, -1e30f);
    float vv = (lane < S_LEN) ? logp : -INFINITY;
    int bi = lane;
    #pragma unroll
    for (int o=32;o;o>>=1) {
      float ov = __shfl_xor(vv, o); int oi = __shfl_xor(bi, o);
      if (ov > vv || (ov == vv && oi < bi)) { vv = ov; bi = oi; }
    }
    int idx = bi;
    if (lane == 0) { out[(size_t)BATCH*S_LEN*S_LEN + b*S_LEN + t] = (float)idx; idx_sh = idx; }
    int mv = 1;
    if (lane < S_LEN) { mv = mask[b*S_LEN+lane]; if (lane==idx) mv = 1; mask[b*S_LEN+lane] = mv; }
    unsigned long long bal = __ballot(mv != 0);
    if ((bal & MASK50) == MASK50 && lane == 49) mask[b*S_LEN+49] = 0;
  }
  __syncthreads();
  int idx = idx_sh;
  xh[(size_t)b*XH_K + tid]        = emb_bf[((size_t)idx*BATCH + b)*HDIM + tid];
  xh[(size_t)XH_Z + (size_t)b*XH_K + tid] = ench_bf[((size_t)idx*BATCH + b)*HDIM + tid];
}

// ---------------------------------------------------------------------------
extern "C" void kernel_launch(void* const* d_in, const int* in_sizes, int n_in,
                              void* d_out, int out_size, void* d_ws, size_t ws_size,
                              hipStream_t stream) {
  (void)in_sizes; (void)n_in; (void)out_size; (void)ws_size;
  const float* dec    = (const float*)d_in[0];
  const float* emb    = (const float*)d_in[1];
  const float* h0     = (const float*)d_in[2];
  const float* c0     = (const float*)d_in[3];
  const float* ctx    = (const float*)d_in[4];
  const float* ench   = (const float*)d_in[5];
  const float* dia    = (const float*)d_in[6];
  const float* h0a    = (const float*)d_in[7];
  const float* c0a    = (const float*)d_in[8];
  const unsigned char* vmask = (const unsigned char*)d_in[9];
  const float* W_ih   = (const float*)d_in[10];
  const float* W_hh   = (const float*)d_in[11];
  const float* b_ih   = (const float*)d_in[12];
  const float* b_hh   = (const float*)d_in[13];
  const float* W_ih_a = (const float*)d_in[14];
  const float* W_hh_a = (const float*)d_in[15];
  const float* b_ih_a = (const float*)d_in[16];
  const float* b_hh_a = (const float*)d_in[17];
  const float* Wq_p  = (const float*)d_in[18];
  const float* bq_p  = (const float*)d_in[19];
  const float* Wr_p  = (const float*)d_in[20];
  const float* br_p  = (const float*)d_in[21];
  const float* v_p   = (const float*)d_in[22];
  const float* Wq_pa = (const float*)d_in[23];
  const float* bq_pa = (const float*)d_in[24];
  const float* Wr_pa = (const float*)d_in[25];
  const float* br_pa = (const float*)d_in[26];
  const float* v_pa  = (const float*)d_in[27];
  const float* Wq_g  = (const float*)d_in[28];
  const float* bq_g  = (const float*)d_in[29];
  const float* Wr_g  = (const float*)d_in[30];
  const float* br_g  = (const float*)d_in[31];
  const float* v_g   = (const float*)d_in[32];
  const float* Wq_ga = (const float*)d_in[33];
  const float* bq_ga = (const float*)d_in[34];
  const float* Wr_ga = (const float*)d_in[35];
  const float* br_ga = (const float*)d_in[36];
  const float* v_ga  = (const float*)d_in[37];

  char* base = (char*)d_ws;
  size_t off = 0;
  auto carve = [&](size_t bytes)->char*{ char* p = base + off; off += (bytes + 255) & ~(size_t)255; return p; };

  const size_t E_BYTES = (size_t)BS*HDIM*2;
  u16* e_g   = (u16*)carve(E_BYTES);
  u16* e_p   = (u16*)carve(E_BYTES);
  u16* e_ga  = (u16*)carve(E_BYTES);
  u16* e_pa  = (u16*)carve(E_BYTES);
  char* scratch = carve(2*E_BYTES);              // A_ctx/A_dia, later emb/ench bf16
  u16* A_ctx  = (u16*)scratch;
  u16* A_dia  = (u16*)(scratch + E_BYTES);
  u16* emb_bf  = A_ctx;
  u16* ench_bf = A_dia;
  u16* Wg      = (u16*)carve((size_t)2*NGATE*XH_K*2);
  float* bsum  = (float*)carve((size_t)2*NGATE*4);
  u16* Wqg_bf  = (u16*)carve((size_t)BH*2);
  u16* Wqga_bf = (u16*)carve((size_t)BH*2);
  u16* Wqp_bf  = (u16*)carve((size_t)BH*2);
  u16* Wqpa_bf = (u16*)carve((size_t)BH*2);
  u16* Wrg_bf  = (u16*)carve((size_t)BH*2);
  u16* Wrp_bf  = (u16*)carve((size_t)BH*2);
  u16* Wrga_bf = (u16*)carve((size_t)BH*2);
  u16* Wrpa_bf = (u16*)carve((size_t)BH*2);
  u16* xh      = (u16*)carve((size_t)2*XH_Z*2);
  float* c_t   = (float*)carve((size_t)2*BH*4);
  u16* gl      = (u16*)carve((size_t)2*BH*2);
  float* q_ws  = (float*)carve((size_t)2*KSPQ*BH*4);
  float* q2_ws = (float*)carve((size_t)2*KSPQ*BH*4);
  int*   mask  = (int*)carve((size_t)BS*4);
  float* out   = (float*)d_out;

  init_kernel<<<1024, 256, 0, stream>>>(h0, c0, h0a, c0a, dec, vmask, xh, c_t, mask);
  mask_fix_kernel<<<BATCH, 64, 0, stream>>>(mask);

  const int RB = ((S_LEN*BATCH*HDIM/4)+255)/256;
  remap_kernel<<<RB, 256, 0, stream>>>(ctx, A_ctx);
  remap_kernel<<<RB, 256, 0, stream>>>(dia, A_dia);
  const int NWG = NGATE*(XH_K/4);
  build_wg_kernel<<<(NWG+255)/256, 256, 0, stream>>>(W_ih,   W_hh,   b_ih,   b_hh,   Wg,                      bsum);
  build_wg_kernel<<<(NWG+255)/256, 256, 0, stream>>>(W_ih_a, W_hh_a, b_ih_a, b_hh_a, Wg + (size_t)NGATE*XH_K, bsum + NGATE);
  const int NWQ = BH/4;
  f2b_kernel<<<(NWQ+255)/256, 256, 0, stream>>>(Wq_g,  Wqg_bf,  NWQ);
  f2b_kernel<<<(NWQ+255)/256, 256, 0, stream>>>(Wq_ga, Wqga_bf, NWQ);
  f2b_kernel<<<(NWQ+255)/256, 256, 0, stream>>>(Wq_p,  Wqp_bf,  NWQ);
  f2b_kernel<<<(NWQ+255)/256, 256, 0, stream>>>(Wq_pa, Wqpa_bf, NWQ);
  f2b_kernel<<<(NWQ+255)/256, 256, 0, stream>>>(Wr_g,  Wrg_bf,  NWQ);
  f2b_kernel<<<(NWQ+255)/256, 256, 0, stream>>>(Wr_p,  Wrp_bf,  NWQ);
  f2b_kernel<<<(NWQ+255)/256, 256, 0, stream>>>(Wr_ga, Wrga_bf, NWQ);
  f2b_kernel<<<(NWQ+255)/256, 256, 0, stream>>>(Wr_pa, Wrpa_bf, NWQ);

  MArgs pa{};
  pa.A[0]=A_ctx; pa.A[1]=A_ctx; pa.A[2]=A_dia; pa.A[3]=A_dia;
  pa.W[0]=Wrg_bf; pa.W[1]=Wrp_bf; pa.W[2]=Wrga_bf; pa.W[3]=Wrpa_bf;
  pa.bias[0]=br_g; pa.bias[1]=br_p; pa.bias[2]=br_ga; pa.bias[3]=br_pa;
  pa.C[0]=e_g; pa.C[1]=e_p; pa.C[2]=e_ga; pa.C[3]=e_pa;
  pa.M=BS; pa.N=HDIM; pa.K=HDIM; pa.lda=HDIM; pa.ksplit=1; pa.out_bf16=1;
  mfma_gemm<<<dim3(4,200,4), 256, 0, stream>>>(pa);

  const int NE = S_LEN*BATCH*HDIM/4;
  f2b_kernel<<<(NE+255)/256, 256, 0, stream>>>(emb,  emb_bf,  NE);
  f2b_kernel<<<(NE+255)/256, 256, 0, stream>>>(ench, ench_bf, NE);

  MArgs qg{};
  qg.A[0]=xh+512; qg.A[1]=xh+XH_Z+512;
  qg.W[0]=Wqg_bf; qg.W[1]=Wqga_bf;
  qg.bias[0]=qg.bias[1]=qg.bias[2]=qg.bias[3]=nullptr;
  qg.C[0]=q_ws; qg.C[1]=q_ws+(size_t)KSPQ*BH;
  qg.M=BATCH; qg.N=HDIM; qg.K=HDIM; qg.lda=XH_K; qg.ksplit=KSPQ; qg.out_bf16=0;

  MArgs qp{};
  qp.A[0]=gl; qp.A[1]=gl+BH;
  qp.W[0]=Wqp_bf; qp.W[1]=Wqpa_bf;
  qp.bias[0]=qp.bias[1]=qp.bias[2]=qp.bias[3]=nullptr;
  qp.C[0]=q2_ws; qp.C[1]=q2_ws+(size_t)KSPQ*BH;
  qp.M=BATCH; qp.N=HDIM; qp.K=HDIM; qp.lda=HDIM; qp.ksplit=KSPQ; qp.out_bf16=0;

  for (int t = 0; t < S_LEN; ++t) {
    lstm_step_kernel<<<dim3(8,16,2), 256, 0, stream>>>(Wg, bsum, xh, c_t);
    mfma_gemm<<<dim3(4,4*KSPQ,2), 256, 0, stream>>>(qg);
    glimpse_kernel<<<dim3(BATCH,2), 512, 0, stream>>>(q_ws, bq_g, bq_ga, e_g, e_ga, v_g, v_ga, mask, gl);
    mfma_gemm<<<dim3(4,4*KSPQ,2), 256, 0, stream>>>(qp);
    pointer_combine_kernel<<<BATCH, 512, 0, stream>>>(q2_ws, bq_p, bq_pa, e_p, e_pa, v_p, v_pa,
                                                      mask, out, t, emb_bf, ench_bf, xh);
  }
}